// Round 23
// baseline (112.219 us; speedup 1.0000x reference)
//
#include <hip/hip_runtime.h>
#include <math.h>

#define NB 4
#define CC 256
#define CO 32
#define NN 4096
#define MU 320   // concat projection rows: 32 q + 32 k + 256 v
#define LOG2E 1.44269504088896f

typedef __attribute__((ext_vector_type(4))) float f4;
typedef __attribute__((ext_vector_type(8))) short s8;          // 8 bf16 MFMA frag
typedef __attribute__((ext_vector_type(8))) unsigned short us8;
typedef __attribute__((ext_vector_type(2))) unsigned int u2;
typedef __attribute__((ext_vector_type(4))) unsigned int u4i;

// fp32 -> bf16 (RNE), scalar fallback
__device__ __forceinline__ unsigned short f2bf(float f) {
    unsigned int u = __float_as_uint(f);
    u = (u + 0x7FFFu + ((u >> 16) & 1u)) >> 16;
    return (unsigned short)u;
}
// HW packed convert: dst = {bf16(lo), bf16(hi)}
__device__ __forceinline__ unsigned int cvtpk(float lo, float hi) {
    unsigned int r;
    asm("v_cvt_pk_bf16_f32 %0, %1, %2" : "=v"(r) : "v"(lo), "v"(hi));
    return r;
}
// XOR-swizzled byte offset within a 128B-row LDS tile (verified round 8)
__device__ __forceinline__ int swz128(int row, int colByte) {
    return row * 128 + (colByte ^ ((row & 7) << 4));
}
// Barrier draining only LDS ops; global prefetch loads stay in flight.
#define LDS_BARRIER() asm volatile("s_waitcnt lgkmcnt(0)\n\ts_barrier" ::: "memory")

union s8u4 { s8 s; u4i u; };

// ---------------------------------------------------------------------------
// prepw: grid 80. Wb[320][256] bf16, fb[320] f32.  (passing, unchanged)
// ---------------------------------------------------------------------------
__global__ __launch_bounds__(256) void prepw_kernel(
    const float* __restrict__ Wq, const float* __restrict__ bq,
    const float* __restrict__ Wk, const float* __restrict__ bk,
    const float* __restrict__ Wv, const float* __restrict__ bv,
    unsigned short* __restrict__ Wb, float* __restrict__ fb)
{
    const int t = threadIdx.x;
    #pragma unroll
    for (int i = 0; i < 4; ++i) {
        const int e = blockIdx.x * 1024 + i * 256 + t;
        const int u = e >> 8, c = e & 255;
        float val = (u < 32) ? Wq[u * 256 + c]
                  : (u < 64) ? Wk[(u - 32) * 256 + c]
                             : Wv[(u - 64) * 256 + c];
        Wb[e] = f2bf(val);
    }
    if (blockIdx.x == 0) {
        for (int u = t; u < MU; u += 256)
            fb[u] = (u < 32) ? bq[u] : (u < 64) ? bk[u - 32] : bv[u - 64];
    }
}

// ---------------------------------------------------------------------------
// projf: fused transpose + MFMA projection.  NOW 1024 blocks (16n each,
// 4 blocks/CU): same total x-traffic, halved per-wave serial chains.
// Stage: xl[16][260] fp32 (2-way write aliasing = free); all 4 waves share
// the 16 n-rows, each wave owns 5 u-tiles (u-split 4 ways).
// ---------------------------------------------------------------------------
__global__ __launch_bounds__(256) void projf_kernel(
    const float* __restrict__ x, const unsigned short* __restrict__ Wb,
    const float* __restrict__ fb,
    unsigned short* __restrict__ qb, unsigned short* __restrict__ kb,
    unsigned short* __restrict__ vtb)
{
    __shared__ float xl[16][260];

    const int t   = threadIdx.x;
    const int b   = blockIdx.x >> 8;
    const int nbl = blockIdx.x & 255;
    const int n0  = nbl * 16;

    {   // stage: thread (c8 = t>>2: c-row, nl = t&3: n-quad) reads f4 along n
        const int nl = t & 3;
        const int c8 = t >> 2;
        #pragma unroll
        for (int pass = 0; pass < 4; ++pass) {
            const int c = c8 + pass * 64;
            f4 xv = *reinterpret_cast<const f4*>(x + ((size_t)(b * CC + c)) * NN + n0 + nl * 4);
            #pragma unroll
            for (int j = 0; j < 4; ++j) xl[nl * 4 + j][c] = xv[j];
        }
    }
    __syncthreads();

    const int w   = t >> 6;       // u-quarter (5 u-tiles each)
    const int l   = t & 63;
    const int l15 = l & 15;
    const int g4  = l >> 4;
    const int n   = n0 + l15;     // all waves share the 16 n-rows

    s8 bfr[8];
    #pragma unroll
    for (int kk = 0; kk < 8; ++kk) {
        f4 a  = *reinterpret_cast<const f4*>(&xl[l15][kk * 32 + g4 * 8]);
        f4 c2 = *reinterpret_cast<const f4*>(&xl[l15][kk * 32 + g4 * 8 + 4]);
        s8u4 tmp;
        tmp.u = (u4i){ cvtpk(a[0], a[1]), cvtpk(a[2], a[3]),
                       cvtpk(c2[0], c2[1]), cvtpk(c2[2], c2[3]) };
        bfr[kk] = tmp.s;
    }

    const f4 z = {0.f, 0.f, 0.f, 0.f};
    unsigned short* qrow = qb + ((size_t)(b * NN + n)) * CO;
    unsigned short* krow = kb + ((size_t)(b * NN + n)) * CO;

    #pragma unroll
    for (int i = 0; i < 5; ++i) {
        const int u0 = (w * 5 + i) * 16;
        f4 acc = z;
        #pragma unroll
        for (int kk = 0; kk < 8; ++kk) {
            s8 af = *reinterpret_cast<const s8*>(Wb + (size_t)(u0 + l15) * CC + kk * 32 + g4 * 8);
            acc = __builtin_amdgcn_mfma_f32_16x16x32_bf16(af, bfr[kk], acc, 0, 0, 0);
        }
        f4 bias4 = *reinterpret_cast<const f4*>(fb + u0 + g4 * 4);
        if (u0 < 32) {
            u2 pw = { cvtpk((acc[0] + bias4[0]) * LOG2E, (acc[1] + bias4[1]) * LOG2E),
                      cvtpk((acc[2] + bias4[2]) * LOG2E, (acc[3] + bias4[3]) * LOG2E) };
            *reinterpret_cast<u2*>(qrow + u0 + g4 * 4) = pw;
        } else if (u0 < 64) {
            u2 pw = { cvtpk(acc[0] + bias4[0], acc[1] + bias4[1]),
                      cvtpk(acc[2] + bias4[2], acc[3] + bias4[3]) };
            *reinterpret_cast<u2*>(krow + (u0 - 32) + g4 * 4) = pw;
        } else {
            const int cbase = u0 - 64 + g4 * 4;
            #pragma unroll
            for (int r = 0; r < 4; ++r)
                vtb[((size_t)(b * CC + cbase + r)) * NN + n] = f2bf(acc[r] + bias4[r]);
        }
    }
}

// ---------------------------------------------------------------------------
// colstats: civ + scaled V in MFMA fragment order (vfr). (passing, unchanged)
// ---------------------------------------------------------------------------
__global__ __launch_bounds__(256) void colstats_kernel(
    const unsigned short* __restrict__ qb, const unsigned short* __restrict__ kb,
    const unsigned short* __restrict__ vtb, unsigned short* __restrict__ vfr)
{
    __shared__ float red[4][16];
    __shared__ float civl[16];

    const int t   = threadIdx.x;
    const int b   = blockIdx.x >> 8;
    const int mb  = blockIdx.x & 255;
    const int l   = t & 63;
    const int w   = t >> 6;
    const int l15 = l & 15;
    const int g4  = l >> 4;
    const int m   = mb * 16 + l15;

    const unsigned short* qbB = qb + (size_t)b * NN * CO;
    s8 kfrag = *reinterpret_cast<const s8*>(kb + ((size_t)b * NN + m) * CO + g4 * 8);

    const f4 z = {0.f, 0.f, 0.f, 0.f};
    float ssum = 0.f;

    const int nbeg = w * 1024, nend = nbeg + 1024;
    for (int n0 = nbeg; n0 < nend; n0 += 32) {
        s8 a0 = *reinterpret_cast<const s8*>(qbB + (size_t)(n0 + l15) * CO + g4 * 8);
        s8 a1 = *reinterpret_cast<const s8*>(qbB + (size_t)(n0 + 16 + l15) * CO + g4 * 8);
        f4 d0 = __builtin_amdgcn_mfma_f32_16x16x32_bf16(a0, kfrag, z, 0, 0, 0);
        f4 d1 = __builtin_amdgcn_mfma_f32_16x16x32_bf16(a1, kfrag, z, 0, 0, 0);
        #pragma unroll
        for (int r = 0; r < 4; ++r) ssum += exp2f(d0[r]) + exp2f(d1[r]);
    }

    ssum += __shfl_xor(ssum, 16);
    ssum += __shfl_xor(ssum, 32);
    if (l < 16) red[w][l15] = ssum;
    __syncthreads();
    if (w == 0 && l < 16)
        civl[l15] = 1.0f / (red[0][l15] + red[1][l15] + red[2][l15] + red[3][l15]);
    __syncthreads();

    const int mt   = mb >> 2;
    const int ksl  = (mb >> 1) & 1;
    const int g4b  = (mb & 1) * 2;
    const int cg   = t >> 4;
    const int l15v = t & 15;
    const unsigned short* vp = vtb + ((size_t)(b * CC + t)) * NN + mb * 16;
    unsigned short* dst = vfr + (size_t)b * 1048576
                        + (((mt * 16 + cg) * 2 + ksl) << 9)
                        + (g4b * 16 + l15v) * 8;
    #pragma unroll
    for (int i = 0; i < 2; ++i) {
        us8 vv = *reinterpret_cast<const us8*>(vp + i * 8);
        u4i o;
        #pragma unroll
        for (int e2 = 0; e2 < 4; ++e2) {
            float f0 = __uint_as_float((unsigned int)vv[2 * e2]     << 16) * civl[i * 8 + 2 * e2];
            float f1 = __uint_as_float((unsigned int)vv[2 * e2 + 1] << 16) * civl[i * 8 + 2 * e2 + 1];
            o[e2] = cvtpk(f0, f1);
        }
        *reinterpret_cast<u4i*>(dst + i * 128) = o;
    }
}

// ---------------------------------------------------------------------------
// attn: round-21 EXACT (best measured: 60.4 us, MfmaUtil 27%, FETCH 9.75MB).
// 32n x 256c blocks, S once, V never duplicated, XCD swizzle, 2 P buffers,
// 1-deep K/V register prefetch, lgkm-only barriers.
// ---------------------------------------------------------------------------
__global__ __launch_bounds__(512, 4) void attn_kernel(
    const unsigned short* __restrict__ qb, const unsigned short* __restrict__ kb,
    const unsigned short* __restrict__ vfr, float* __restrict__ out)
{
    __shared__ __align__(16) char plds[2][32 * 128];   // P tile [32n][64m] bf16, swizzled

    const int t   = threadIdx.x;
    const int w   = t >> 6;
    const int l   = t & 63;
    const int l15 = l & 15;
    const int g4  = l >> 4;
    // XCD swizzle: bijective (512 % 8 == 0); 64 consecutive works per XCD
    const int bid  = (blockIdx.x & 7) * 64 + (blockIdx.x >> 3);
    const int b    = bid >> 7;
    const int nblk = bid & 127;
    const int n0   = nblk * 32;
    const int ng   = w >> 2;      // S n-group (16 rows)
    const int mq   = w & 3;       // S m-quarter (16 m)

    const unsigned short* qbB = qb + (size_t)b * NN * CO;
    const unsigned short* kbB = kb + (size_t)b * NN * CO;

    // wave's 16 S-rows (B-operand of swapped MFMA)
    s8 qfrag = *reinterpret_cast<const s8*>(qbB + (size_t)(n0 + ng * 16 + l15) * CO + g4 * 8);

    // ---- loop-invariant LDS byte offsets ----
    const int pwo  = swz128(ng * 16 + l15, mq * 32 + g4 * 8);   // P write (u2)
    const int pr00 = swz128(l15,      g4 * 16);                 // pa[nt0][ksl0]
    const int pr01 = swz128(l15,      64 + g4 * 16);            // pa[nt0][ksl1]
    const int pr10 = swz128(16 + l15, g4 * 16);                 // pa[nt1][ksl0]
    const int pr11 = swz128(16 + l15, 64 + g4 * 16);            // pa[nt1][ksl1]

    // ---- incremental global pointers ----
    const unsigned short* kp = kbB + (size_t)(mq * 16 + l15) * CO + g4 * 8;
    // vfr: chunk (mt, cg = w*2 + ct, ksl) at ((mt*16+cg)*2+ksl)*512 + lane*8
    const unsigned short* vp = vfr + (size_t)b * 1048576 + w * 2048 + l * 8;

    s8 kreg;
    s8 v0, v1, v2, v3;       // [ct*2 + ksl]
    const f4 z = {0.f, 0.f, 0.f, 0.f};
    f4 acc00 = z, acc01 = z, acc10 = z, acc11 = z;   // [nt][ct]

#define LOADK() do { kreg = *reinterpret_cast<const s8*>(kp); kp += 2048; } while (0)
#define LOADV() do { \
        v0 = *reinterpret_cast<const s8*>(vp); \
        v1 = *reinterpret_cast<const s8*>(vp + 512); \
        v2 = *reinterpret_cast<const s8*>(vp + 1024); \
        v3 = *reinterpret_cast<const s8*>(vp + 1536); \
        vp += 16384; \
    } while (0)

#define STAGE(BUF, KR) do { \
        f4 d = __builtin_amdgcn_mfma_f32_16x16x32_bf16(KR, qfrag, z, 0, 0, 0); \
        u2 pw = { cvtpk(exp2f(d[0]), exp2f(d[1])), cvtpk(exp2f(d[2]), exp2f(d[3])) }; \
        *reinterpret_cast<u2*>(plds[BUF] + pwo) = pw; \
    } while (0)

#define PVSTEP(BUF) do { \
        s8 pa00 = *reinterpret_cast<const s8*>(plds[BUF] + pr00); \
        s8 pa01 = *reinterpret_cast<const s8*>(plds[BUF] + pr01); \
        s8 pa10 = *reinterpret_cast<const s8*>(plds[BUF] + pr10); \
        s8 pa11 = *reinterpret_cast<const s8*>(plds[BUF] + pr11); \
        __builtin_amdgcn_s_setprio(1); \
        acc00 = __builtin_amdgcn_mfma_f32_16x16x32_bf16(pa00, v0, acc00, 0, 0, 0); \
        acc01 = __builtin_amdgcn_mfma_f32_16x16x32_bf16(pa00, v2, acc01, 0, 0, 0); \
        acc10 = __builtin_amdgcn_mfma_f32_16x16x32_bf16(pa10, v0, acc10, 0, 0, 0); \
        acc11 = __builtin_amdgcn_mfma_f32_16x16x32_bf16(pa10, v2, acc11, 0, 0, 0); \
        acc00 = __builtin_amdgcn_mfma_f32_16x16x32_bf16(pa01, v1, acc00, 0, 0, 0); \
        acc01 = __builtin_amdgcn_mfma_f32_16x16x32_bf16(pa01, v3, acc01, 0, 0, 0); \
        acc10 = __builtin_amdgcn_mfma_f32_16x16x32_bf16(pa11, v1, acc10, 0, 0, 0); \
        acc11 = __builtin_amdgcn_mfma_f32_16x16x32_bf16(pa11, v3, acc11, 0, 0, 0); \
        __builtin_amdgcn_s_setprio(0); \
    } while (0)

    // prologue: K0 (temp), K1 -> kreg, V0 -> vregs, stage P0
    s8 k0 = *reinterpret_cast<const s8*>(kp); kp += 2048;   // K(0)
    LOADK();                                                // kreg = K(1)
    LOADV();                                                // V(0)
    STAGE(0, k0);                                           // P(0)
    LDS_BARRIER();

    for (int i = 0; i < 64; i += 2) {
        STAGE(1, kreg);                 // P(i+1)
        if (i < 62) LOADK();            // K(i+2)
        PVSTEP(0);                      // tile i   (uses V(i))
        if (i < 63) LOADV();            // V(i+1)
        LDS_BARRIER();

        if (i + 1 < 63) STAGE(0, kreg); // P(i+2)
        if (i + 1 < 62) LOADK();        // K(i+3)
        PVSTEP(1);                      // tile i+1 (uses V(i+1))
        if (i + 1 < 63) LOADV();        // V(i+2)
        LDS_BARRIER();
    }

#undef LOADK
#undef LOADV
#undef STAGE
#undef PVSTEP

    // D layout: col = lane&15 -> c, row = g4*4 + r -> n
    float* ob = out + (size_t)b * NN * CC;
    const int cw = w * 32 + l15;
    #pragma unroll
    for (int r = 0; r < 4; ++r) {
        const size_t row0 = (size_t)(n0 + g4 * 4 + r) * CC;
        const size_t row1 = (size_t)(n0 + 16 + g4 * 4 + r) * CC;
        ob[row0 + cw]      = acc00[r];
        ob[row0 + cw + 16] = acc01[r];
        ob[row1 + cw]      = acc10[r];
        ob[row1 + cw + 16] = acc11[r];
    }
}

extern "C" void kernel_launch(void* const* d_in, const int* in_sizes, int n_in,
                              void* d_out, int out_size, void* d_ws, size_t ws_size,
                              hipStream_t stream)
{
    const float* x  = (const float*)d_in[0];
    const float* Wq = (const float*)d_in[1];
    const float* bq = (const float*)d_in[2];
    const float* Wk = (const float*)d_in[3];
    const float* bk = (const float*)d_in[4];
    const float* Wv = (const float*)d_in[5];
    const float* bv = (const float*)d_in[6];
    float* out = (float*)d_out;

    // ws layout: qb(1MB) | kb(1MB) | vtb(8MB) | vfr(8MB) | Wb(160KB) | fb
    unsigned short* qb  = (unsigned short*)d_ws;
    unsigned short* kb  = qb  + (size_t)NB * NN * CO;
    unsigned short* vtb = kb  + (size_t)NB * NN * CO;
    unsigned short* vfr = vtb + (size_t)NB * CC * NN;
    unsigned short* Wb  = vfr + (size_t)NB * CC * NN;
    float*          fb  = (float*)(Wb + (size_t)MU * CC);

    prepw_kernel<<<dim3(80), dim3(256), 0, stream>>>(Wq, bq, Wk, bk, Wv, bv, Wb, fb);
    projf_kernel<<<dim3(1024), dim3(256), 0, stream>>>(x, Wb, fb, qb, kb, vtb);
    colstats_kernel<<<dim3(1024), dim3(256), 0, stream>>>(qb, kb, vtb, vfr);
    attn_kernel<<<dim3(512), dim3(512), 0, stream>>>(qb, kb, vfr, out);
}